// Round 12
// baseline (326.460 us; speedup 1.0000x reference)
//
#include <hip/hip_runtime.h>
#include <hip/hip_bf16.h>
#include <math.h>

#define NN 1536
#define TT 10
#define DD 64
#define NHEAD 4
#define HDIM 16
#define PP 1178880   // NN*(NN-1)/2 = 4605 * 256 exactly; = 18420 * 64
#define JSPLIT 4

// ws layout (float offsets) — lifetime-overlapped, total 727040 (proven safe):
//   W2F    0       (8192)
//   TXYT   8192    (30720)  -> 38912
//   PART   38912   (393216) -> 432128  [post-red3: row i floats 0..128 = gi, stride 256]
//   GJT4   432128  (196608) -> 628736  [g1b lives here during layers 1-2]
//   SLOTA  628736  (98304)  -> 727040  [node0 -> g2b -> whf (4096 floats)]
#define WS_W2F   0
#define WS_TXYT  8192
#define WS_PART  38912
#define WS_GJT4  432128
#define WS_SLOTA 628736

using bf16x8 = __attribute__((ext_vector_type(8))) short;
using f32x4  = __attribute__((ext_vector_type(4))) float;

static __device__ __forceinline__ float fsqrt(float x) { return __builtin_amdgcn_sqrtf(x); }
static __device__ __forceinline__ float frcp(float x)  { return __builtin_amdgcn_rcpf(x); }
static __device__ __forceinline__ float fexp(float x)  {
    return __builtin_amdgcn_exp2f(x * 1.44269504088896f);
}
static __device__ __forceinline__ float fsigmoid_neg(float e_arg) {
    return frcp(1.f + fexp(e_arg));     // 1/(1+exp(e_arg))
}

static __device__ __forceinline__ unsigned short f2bf_rn(float f) {
    unsigned int u = __float_as_uint(f);
    unsigned int r = (u + 0x7FFFu + ((u >> 16) & 1u)) >> 16;
    return (unsigned short)r;
}
static __device__ __forceinline__ float bf2f(unsigned short h) {
    return __uint_as_float(((unsigned int)h) << 16);
}

static __device__ __forceinline__ float dot64(const float* __restrict__ a,
                                              const float* __restrict__ b) {
    float s = 0.f;
#pragma unroll
    for (int c = 0; c < 64; c += 4) {
        float4 av = *reinterpret_cast<const float4*>(a + c);
        float4 bv = *reinterpret_cast<const float4*>(b + c);
        s = fmaf(av.x, bv.x, s);
        s = fmaf(av.y, bv.y, s);
        s = fmaf(av.z, bv.z, s);
        s = fmaf(av.w, bv.w, s);
    }
    return s;
}

static __device__ __forceinline__ void invert_p(int p, int& io, int& jo) {
    const float Df = (float)((2 * NN - 1) * (2 * NN - 1) - 8 * p);
    int i = (int)(((float)(2 * NN - 1) - fsqrt(Df)) * 0.5f);
    i = i < 0 ? 0 : (i > NN - 2 ? NN - 2 : i);
    while (i * (2 * NN - 1 - i) / 2 > p) --i;
    while ((i + 1) * (2 * NN - 2 - i) / 2 <= p) ++i;
    io = i;
    jo = i + 1 + (p - i * (2 * NN - 1 - i) / 2);
}

// accumulate 16-wide chunk: acc += x[0..15] . w(4 float4 regs)
#define FMA16(acc, xr, w0, w1, w2, w3)                                   \
    {                                                                    \
        float4 x0 = *reinterpret_cast<const float4*>(xr);                \
        float4 x1 = *reinterpret_cast<const float4*>(xr + 4);            \
        float4 x2 = *reinterpret_cast<const float4*>(xr + 8);            \
        float4 x3 = *reinterpret_cast<const float4*>(xr + 12);           \
        acc = fmaf(x0.x, w0.x, acc); acc = fmaf(x0.y, w0.y, acc);        \
        acc = fmaf(x0.z, w0.z, acc); acc = fmaf(x0.w, w0.w, acc);        \
        acc = fmaf(x1.x, w1.x, acc); acc = fmaf(x1.y, w1.y, acc);        \
        acc = fmaf(x1.z, w1.z, acc); acc = fmaf(x1.w, w1.w, acc);        \
        acc = fmaf(x2.x, w2.x, acc); acc = fmaf(x2.y, w2.y, acc);        \
        acc = fmaf(x2.z, w2.z, acc); acc = fmaf(x2.w, w2.w, acc);        \
        acc = fmaf(x3.x, w3.x, acc); acc = fmaf(x3.y, w3.y, acc);        \
        acc = fmaf(x3.z, w3.z, acc); acc = fmaf(x3.w, w3.w, acc);        \
    }

// ---------------- Transformer encoder layer (+aux: w2f, txyT), 128 thr/block ----------------
__global__ __launch_bounds__(128) void k_transformer(
    const float* __restrict__ traj,
    const float* __restrict__ wqkv, const float* __restrict__ bqkv,
    const float* __restrict__ wo,   const float* __restrict__ bo,
    const float* __restrict__ g1,   const float* __restrict__ b1,
    const float* __restrict__ fw1,  const float* __restrict__ fb1,
    const float* __restrict__ fw2,  const float* __restrict__ fb2,
    const float* __restrict__ g2,   const float* __restrict__ b2,
    const float* __restrict__ e_w2,
    float* __restrict__ node_out, unsigned short* __restrict__ w2f,
    float* __restrict__ txyT)
{
    const int bid = blockIdx.x, tid = threadIdx.x;

    if (bid >= NN) {
        const int s = bid - NN;
        if (s < 64) {
#pragma unroll
            for (int q = 0; q < 2; ++q) {
                const int idx = s * 256 + q * 128 + tid;
                int e = idx & 7, lane = (idx >> 3) & 63;
                int half = (idx >> 9) & 1, kk = (idx >> 10) & 3, nt = (idx >> 12) & 3;
                int n = nt * 16 + (lane & 15);
                int k = kk * 32 + (lane >> 4) * 8 + e;
                float v = e_w2[n * 128 + k];
                unsigned short hi = f2bf_rn(v);
                unsigned short lo = f2bf_rn(v - bf2f(hi));
                w2f[idx] = half ? lo : hi;
            }
        } else {
            const int tc = s - 64;       // 0..19
            const int t = tc >> 1, c = tc & 1;
            for (int j = tid; j < NN; j += 128)
                txyT[(size_t)tc * NN + j] = traj[((size_t)j * TT + t) * DD + c];
        }
        return;
    }

    __shared__ __align__(16) float xs[TT][DD];
    __shared__ __align__(16) float qkvs[TT][3 * DD];
    __shared__ __align__(16) float cs[TT][DD];
    __shared__ __align__(16) float ys[TT][DD];
    __shared__ float mv[TT][2];

    const float* xg = traj + (size_t)bid * TT * DD;
    for (int idx = tid; idx < TT * DD; idx += 128)
        xs[idx / DD][idx % DD] = xg[idx];
    __syncthreads();

    // ---- QKV ----
    {
        float acc[TT];
        const float bq = bqkv[tid];
#pragma unroll
        for (int t = 0; t < TT; ++t) acc[t] = bq;
        const float* wrow = wqkv + (size_t)tid * DD;
#pragma unroll
        for (int c = 0; c < 4; ++c) {
            float4 w0 = *reinterpret_cast<const float4*>(wrow + 16 * c);
            float4 w1 = *reinterpret_cast<const float4*>(wrow + 16 * c + 4);
            float4 w2 = *reinterpret_cast<const float4*>(wrow + 16 * c + 8);
            float4 w3 = *reinterpret_cast<const float4*>(wrow + 16 * c + 12);
#pragma unroll
            for (int t = 0; t < TT; ++t)
                FMA16(acc[t], &xs[t][16 * c], w0, w1, w2, w3);
        }
#pragma unroll
        for (int t = 0; t < TT; ++t) qkvs[t][tid] = acc[t];

        const int o2 = 128 + (tid >> 1);
        const int t0 = (tid & 1) * 5;
        float acc2[5];
        const float bq2 = bqkv[o2];
#pragma unroll
        for (int tt = 0; tt < 5; ++tt) acc2[tt] = bq2;
        const float* wrow2 = wqkv + (size_t)o2 * DD;
#pragma unroll
        for (int c = 0; c < 4; ++c) {
            float4 w0 = *reinterpret_cast<const float4*>(wrow2 + 16 * c);
            float4 w1 = *reinterpret_cast<const float4*>(wrow2 + 16 * c + 4);
            float4 w2 = *reinterpret_cast<const float4*>(wrow2 + 16 * c + 8);
            float4 w3 = *reinterpret_cast<const float4*>(wrow2 + 16 * c + 12);
#pragma unroll
            for (int tt = 0; tt < 5; ++tt)
                FMA16(acc2[tt], &xs[t0 + tt][16 * c], w0, w1, w2, w3);
        }
#pragma unroll
        for (int tt = 0; tt < 5; ++tt) qkvs[t0 + tt][o2] = acc2[tt];
    }
    __syncthreads();

    // ---- attention ----
    if (tid < NHEAD * TT) {
        int h = tid / TT, t = tid % TT;
        float sc[TT];
        float mx = -1e30f;
#pragma unroll
        for (int s = 0; s < TT; ++s) {
            float a = 0.f;
#pragma unroll
            for (int d = 0; d < HDIM; ++d)
                a = fmaf(qkvs[t][h * HDIM + d], qkvs[s][DD + h * HDIM + d], a);
            a *= 0.25f;
            sc[s] = a;
            mx = fmaxf(mx, a);
        }
        float den = 0.f;
#pragma unroll
        for (int s = 0; s < TT; ++s) { sc[s] = fexp(sc[s] - mx); den += sc[s]; }
        float inv = frcp(den);
#pragma unroll
        for (int d = 0; d < HDIM; ++d) {
            float a = 0.f;
#pragma unroll
            for (int s = 0; s < TT; ++s)
                a = fmaf(sc[s], qkvs[s][2 * DD + h * HDIM + d], a);
            cs[t][h * HDIM + d] = a * inv;
        }
    }
    __syncthreads();

    // ---- out-proj + residual ----
    {
        const int o = tid & 63, t0 = (tid >> 6) * 5;
        float acc[5];
        const float bv = bo[o];
#pragma unroll
        for (int tt = 0; tt < 5; ++tt) acc[tt] = bv;
        const float* wrow = wo + (size_t)o * DD;
#pragma unroll
        for (int c = 0; c < 4; ++c) {
            float4 w0 = *reinterpret_cast<const float4*>(wrow + 16 * c);
            float4 w1 = *reinterpret_cast<const float4*>(wrow + 16 * c + 4);
            float4 w2 = *reinterpret_cast<const float4*>(wrow + 16 * c + 8);
            float4 w3 = *reinterpret_cast<const float4*>(wrow + 16 * c + 12);
#pragma unroll
            for (int tt = 0; tt < 5; ++tt)
                FMA16(acc[tt], &cs[t0 + tt][16 * c], w0, w1, w2, w3);
        }
#pragma unroll
        for (int tt = 0; tt < 5; ++tt)
            ys[t0 + tt][o] = xs[t0 + tt][o] + acc[tt];
    }
    __syncthreads();

    // ---- LN1 stats ----
    {
        const int t8 = tid >> 3, s8 = tid & 7;
        if (t8 < TT) {
            const float* yr = &ys[t8][s8 * 8];
            float s1 = 0.f;
#pragma unroll
            for (int c = 0; c < 8; c += 4) {
                float4 v = *reinterpret_cast<const float4*>(yr + c);
                s1 += (v.x + v.y) + (v.z + v.w);
            }
#pragma unroll
            for (int m = 1; m < 8; m <<= 1) s1 += __shfl_xor(s1, m);
            const float mean = s1 * (1.f / DD);
            float s2 = 0.f;
#pragma unroll
            for (int c = 0; c < 8; c += 4) {
                float4 v = *reinterpret_cast<const float4*>(yr + c);
                float d0 = v.x - mean, d1 = v.y - mean, d2 = v.z - mean, d3 = v.w - mean;
                s2 = fmaf(d0, d0, fmaf(d1, d1, fmaf(d2, d2, fmaf(d3, d3, s2))));
            }
#pragma unroll
            for (int m = 1; m < 8; m <<= 1) s2 += __shfl_xor(s2, m);
            if (s8 == 0) {
                mv[t8][0] = mean;
                mv[t8][1] = rsqrtf(s2 * (1.f / DD) + 1e-5f);
            }
        }
    }
    __syncthreads();
    for (int idx = tid; idx < TT * DD; idx += 128) {
        int t = idx / DD, o = idx % DD;
        xs[t][o] = (ys[t][o] - mv[t][0]) * mv[t][1] * g1[o] + b1[o];
    }
    __syncthreads();

    // ---- FF1 ----
    {
        const int pcol = tid & 63, t0 = (tid >> 6) * 5;
        float acc[5];
        const float bv = fb1[pcol];
#pragma unroll
        for (int tt = 0; tt < 5; ++tt) acc[tt] = bv;
        const float* wrow = fw1 + (size_t)pcol * DD;
#pragma unroll
        for (int c = 0; c < 4; ++c) {
            float4 w0 = *reinterpret_cast<const float4*>(wrow + 16 * c);
            float4 w1 = *reinterpret_cast<const float4*>(wrow + 16 * c + 4);
            float4 w2 = *reinterpret_cast<const float4*>(wrow + 16 * c + 8);
            float4 w3 = *reinterpret_cast<const float4*>(wrow + 16 * c + 12);
#pragma unroll
            for (int tt = 0; tt < 5; ++tt)
                FMA16(acc[tt], &xs[t0 + tt][16 * c], w0, w1, w2, w3);
        }
#pragma unroll
        for (int tt = 0; tt < 5; ++tt)
            cs[t0 + tt][pcol] = fmaxf(acc[tt], 0.f);
    }
    __syncthreads();

    // ---- FF2 + residual ----
    {
        const int o = tid & 63, t0 = (tid >> 6) * 5;
        float acc[5];
        const float bv = fb2[o];
#pragma unroll
        for (int tt = 0; tt < 5; ++tt) acc[tt] = bv;
        const float* wrow = fw2 + (size_t)o * DD;
#pragma unroll
        for (int c = 0; c < 4; ++c) {
            float4 w0 = *reinterpret_cast<const float4*>(wrow + 16 * c);
            float4 w1 = *reinterpret_cast<const float4*>(wrow + 16 * c + 4);
            float4 w2 = *reinterpret_cast<const float4*>(wrow + 16 * c + 8);
            float4 w3 = *reinterpret_cast<const float4*>(wrow + 16 * c + 12);
#pragma unroll
            for (int tt = 0; tt < 5; ++tt)
                FMA16(acc[tt], &cs[t0 + tt][16 * c], w0, w1, w2, w3);
        }
#pragma unroll
        for (int tt = 0; tt < 5; ++tt)
            ys[t0 + tt][o] = xs[t0 + tt][o] + acc[tt];
    }
    __syncthreads();

    // ---- LN2 stats ----
    {
        const int t8 = tid >> 3, s8 = tid & 7;
        if (t8 < TT) {
            const float* yr = &ys[t8][s8 * 8];
            float s1 = 0.f;
#pragma unroll
            for (int c = 0; c < 8; c += 4) {
                float4 v = *reinterpret_cast<const float4*>(yr + c);
                s1 += (v.x + v.y) + (v.z + v.w);
            }
#pragma unroll
            for (int m = 1; m < 8; m <<= 1) s1 += __shfl_xor(s1, m);
            const float mean = s1 * (1.f / DD);
            float s2 = 0.f;
#pragma unroll
            for (int c = 0; c < 8; c += 4) {
                float4 v = *reinterpret_cast<const float4*>(yr + c);
                float d0 = v.x - mean, d1 = v.y - mean, d2 = v.z - mean, d3 = v.w - mean;
                s2 = fmaf(d0, d0, fmaf(d1, d1, fmaf(d2, d2, fmaf(d3, d3, s2))));
            }
#pragma unroll
            for (int m = 1; m < 8; m <<= 1) s2 += __shfl_xor(s2, m);
            if (s8 == 0) {
                mv[t8][0] = mean;
                mv[t8][1] = rsqrtf(s2 * (1.f / DD) + 1e-5f);
            }
        }
    }
    __syncthreads();

    if (tid < DD) {
        float acc = 0.f;
#pragma unroll
        for (int t = 0; t < TT; ++t)
            acc += (ys[t][tid] - mv[t][0]) * mv[t][1];
        node_out[bid * DD + tid] = acc * g2[tid] * (1.f / TT) + b2[tid];
    }
}

// ---------------- GCN: partial A@X over j-chunk; part layout [i][jc][64] ----------------
__global__ __launch_bounds__(256) void k_gcn_part(
    const float* __restrict__ A, const float* __restrict__ X,
    float* __restrict__ part)
{
    const int tid = threadIdx.x;
    const int r = tid >> 5;
    const int cp = tid & 31;
    const int i = blockIdx.x * 8 + r;
    const int jc = blockIdx.y;
    const int j0 = jc * (NN / JSPLIT);

    const float* arow = A + (size_t)i * NN + j0;
    const float* xp = X + (size_t)j0 * 64 + 2 * cp;

    float a0 = 0.f, a1 = 0.f;
#pragma unroll 4
    for (int j = 0; j < NN / JSPLIT; ++j) {
        float av = arow[j];
        float2 xv = *reinterpret_cast<const float2*>(xp + (size_t)j * 64);
        a0 = fmaf(av, xv.x, a0);
        a1 = fmaf(av, xv.y, a1);
    }
    float2* op = reinterpret_cast<float2*>(part + ((size_t)i * JSPLIT + jc) * 64 + 2 * cp);
    *op = make_float2(a0, a1);
}

// ---------------- GCN red (layers 1,2) ----------------
__global__ __launch_bounds__(256) void k_gcn_red(
    const float* __restrict__ part, const float* __restrict__ W,
    const float* __restrict__ b, float* __restrict__ Y)
{
    __shared__ __align__(16) float yrow[4][68];
    const int o = threadIdx.x & 63, r = threadIdx.x >> 6;
    const int i = blockIdx.x * 4 + r;

    float s = 0.f;
#pragma unroll
    for (int jc = 0; jc < JSPLIT; ++jc)
        s += part[((size_t)i * JSPLIT + jc) * 64 + o];
    yrow[r][o] = s;
    __syncthreads();

    float z = b[o] + dot64(&yrow[r][0], W + o * 64);
    Y[(size_t)i * 64 + o] = fmaxf(z, 0.f);
}

// ---------------- GCN red layer 3 + fused edge-prep (gi into part rows, gjT4, whf) ----------------
__global__ __launch_bounds__(256) void k_gcn_red3(
    float* __restrict__ part, const float* __restrict__ W,
    const float* __restrict__ b,
    const float* __restrict__ e_w1, const float* __restrict__ e_b1,
    float* __restrict__ gjT4, unsigned int* __restrict__ whf32)
{
    __shared__ __align__(16) float yrow[4][68];
    __shared__ __align__(16) float nrow[4][68];
    const int tid = threadIdx.x;
    const int o = tid & 63, r = tid >> 6;
    const int i0 = blockIdx.x * 4;

    float s = 0.f;
#pragma unroll
    for (int jc = 0; jc < JSPLIT; ++jc)
        s += part[((size_t)(i0 + r) * JSPLIT + jc) * 64 + o];
    yrow[r][o] = s;
    __syncthreads();

    float z = b[o] + dot64(&yrow[r][0], W + o * 64);
    nrow[r][o] = fmaxf(z, 0.f);
    __syncthreads();

    // gi into part's own rows (stride 256), gjT4 quad layout
#pragma unroll
    for (int pass = 0; pass < 2; ++pass) {
        const int idx = pass * 256 + tid;
        const int rr = idx >> 7, oo = idx & 127;
        part[(size_t)(i0 + rr) * 256 + oo] =
            e_b1[oo] + dot64(&nrow[rr][0], e_w1 + oo * 138);
    }
#pragma unroll
    for (int pass = 0; pass < 2; ++pass) {
        const int idx = pass * 256 + tid;
        const int rr = idx >> 7, oo = idx & 127;
        float v = dot64(&nrow[rr][0], e_w1 + oo * 138 + 64);
        gjT4[((size_t)(oo >> 2) * NN + (i0 + rr)) * 4 + (oo & 3)] = v;
    }

    // whf table: whT MFMA A-frags (hi/lo trunc split), blocks 0..7 build 512 u32 each
    if (blockIdx.x < 8) {
#pragma unroll
        for (int w = 0; w < 2; ++w) {
            const int g = blockIdx.x * 512 + w * 256 + tid;   // u32 index < 4096
            const int u = g * 2;
            const int ln = (u >> 3) & 63, hf = (u >> 9) & 1, ot = (u >> 10) & 7;
            const int oo = ot * 16 + (ln & 15);
            const int k0 = (ln >> 4) * 8 + (u & 7);
            unsigned int rr = 0;
#pragma unroll
            for (int q = 0; q < 2; ++q) {
                const int k = k0 + q;
                float v = (k < 10) ? e_w1[oo * 138 + 128 + k] : 0.f;
                unsigned int uu = __float_as_uint(v);
                unsigned int bf = (hf == 0)
                    ? (uu >> 16)
                    : (__float_as_uint(v - __uint_as_float(uu & 0xFFFF0000u)) >> 16);
                rr |= (bf & 0xFFFFu) << (16 * q);
            }
            whf32[g] = rr;
        }
    }
}

// ---------------- edge predictor: MFMA L1(hist) + MFMA L2, half-K, 64 pairs/block ----------------
__global__ __launch_bounds__(256, 6) void k_edge(
    const float* __restrict__ txyT,
    const float* __restrict__ gi_t,      // stride 256 per i (part rows)
    const float* __restrict__ gjT4,
    const unsigned short* __restrict__ whf,
    const unsigned short* __restrict__ w2f,
    const float* __restrict__ e_b2,
    const float* __restrict__ e_w3, const float* __restrict__ e_b3,
    float* __restrict__ out)
{
    __shared__ __align__(16) unsigned short Ah[64 * 64];
    __shared__ __align__(16) unsigned short Al[64 * 64];
    __shared__ __align__(16) unsigned int hsbh[64 * 8];
    __shared__ __align__(16) unsigned int hsbl[64 * 8];
    __shared__ float zsh[4][64];

    const int tid  = threadIdx.x;
    const int lane = tid & 63;
    const int wv   = __builtin_amdgcn_readfirstlane(tid >> 6);
    const int kg   = lane >> 4;          // 0..3
    const int n16  = lane & 15;
    const int pbase = blockIdx.x * 64;

    // ---- wave 0: hist + dmin + stores + hsb (bf16 hi/lo B-frag tables) ----
    if (wv == 0) {
        int pi, pj;
        invert_p(pbase + lane, pi, pj);
        float hist[10];
        float dmin = 3.4e38f;
#pragma unroll
        for (int t = 0; t < 10; ++t) {
            float dx = txyT[(size_t)(2 * t) * NN + pi] - txyT[(size_t)(2 * t) * NN + pj];
            float dy = txyT[(size_t)(2 * t + 1) * NN + pi] - txyT[(size_t)(2 * t + 1) * NN + pj];
            float d = fsqrt(fmaf(dx, dx, dy * dy));
            dmin = fminf(dmin, d);
            hist[t] = fsigmoid_neg(50.f - 10.f * d);
        }
        out[PP + (size_t)(pbase + lane)] = dmin;
        float* hp = out + 2 * (size_t)PP + (size_t)(pbase + lane) * 10;
#pragma unroll
        for (int t = 0; t < 10; ++t) hp[t] = hist[t];

        unsigned int uh[10], ul[10];
#pragma unroll
        for (int t = 0; t < 10; ++t) {
            unsigned int u = __float_as_uint(hist[t]) & 0xFFFF0000u;
            uh[t] = u;
            ul[t] = __float_as_uint(hist[t] - __uint_as_float(u));
        }
        uint4 v0, v1;
        v0.x = __builtin_amdgcn_perm(uh[1], uh[0], 0x07060302);
        v0.y = __builtin_amdgcn_perm(uh[3], uh[2], 0x07060302);
        v0.z = __builtin_amdgcn_perm(uh[5], uh[4], 0x07060302);
        v0.w = __builtin_amdgcn_perm(uh[7], uh[6], 0x07060302);
        v1.x = __builtin_amdgcn_perm(uh[9], uh[8], 0x07060302);
        v1.y = 0u; v1.z = 0u; v1.w = 0u;
        *reinterpret_cast<uint4*>(&hsbh[lane * 8])     = v0;
        *reinterpret_cast<uint4*>(&hsbh[lane * 8 + 4]) = v1;
        v0.x = __builtin_amdgcn_perm(ul[1], ul[0], 0x07060302);
        v0.y = __builtin_amdgcn_perm(ul[3], ul[2], 0x07060302);
        v0.z = __builtin_amdgcn_perm(ul[5], ul[4], 0x07060302);
        v0.w = __builtin_amdgcn_perm(ul[7], ul[6], 0x07060302);
        v1.x = __builtin_amdgcn_perm(ul[9], ul[8], 0x07060302);
        *reinterpret_cast<uint4*>(&hsbl[lane * 8])     = v0;
        *reinterpret_cast<uint4*>(&hsbl[lane * 8 + 4]) = v1;
    }

    // this thread's GEMM pair
    int pi2, pj2;
    const int prow = wv * 16 + n16;      // pair-local row 0..63
    invert_p(pbase + prow, pi2, pj2);
    __syncthreads();                     // barrier A: hsb ready

    // hist B-frags (k = kg*8 + e; zero for kg >= 2)
    const uint4 z4 = make_uint4(0u, 0u, 0u, 0u);
    uint4 bh4 = (kg < 2) ? *reinterpret_cast<const uint4*>(&hsbh[prow * 8 + kg * 4]) : z4;
    uint4 bl4 = (kg < 2) ? *reinterpret_cast<const uint4*>(&hsbl[prow * 8 + kg * 4]) : z4;
    const bf16x8 bhisth = *reinterpret_cast<const bf16x8*>(&bh4);
    const bf16x8 bhistl = *reinterpret_cast<const bf16x8*>(&bl4);

    f32x4 accM[4];
#pragma unroll
    for (int pt = 0; pt < 4; ++pt) accM[pt] = (f32x4){0.f, 0.f, 0.f, 0.f};

    const float* giRow = gi_t + (size_t)pi2 * 256;
    char* ahb = (char*)Ah + prow * 128;
    char* alb = (char*)Al + prow * 128;

#pragma unroll
    for (int h = 0; h < 2; ++h) {
        if (h == 1) __syncthreads();     // barrier C: half-0 reads done before overwrite

        // ---- L1 via MFMA: 4 o-tiles of 16, epilogue + LDS write ----
#pragma unroll
        for (int otl = 0; otl < 4; ++otl) {
            const int ot = h * 4 + otl;
            const unsigned short* wp = whf + (size_t)(ot * 2) * 512 + lane * 8;
            bf16x8 wfh = *reinterpret_cast<const bf16x8*>(wp);
            bf16x8 wfl = *reinterpret_cast<const bf16x8*>(wp + 512);
            f32x4 a1 = (f32x4){0.f, 0.f, 0.f, 0.f};
            a1 = __builtin_amdgcn_mfma_f32_16x16x32_bf16(wfh, bhisth, a1, 0, 0, 0);
            a1 = __builtin_amdgcn_mfma_f32_16x16x32_bf16(wfh, bhistl, a1, 0, 0, 0);
            a1 = __builtin_amdgcn_mfma_f32_16x16x32_bf16(wfl, bhisth, a1, 0, 0, 0);

            const float4 gi4 = *reinterpret_cast<const float4*>(giRow + ot * 16 + kg * 4);
            const float4 gj4 = *reinterpret_cast<const float4*>(
                gjT4 + ((size_t)(ot * 4 + kg) * NN + pj2) * 4);
            float av[4];
#pragma unroll
            for (int r = 0; r < 4; ++r)
                av[r] = fmaxf(a1[r] + (&gi4.x)[r] + (&gj4.x)[r], 0.f);

            const unsigned int u0 = __float_as_uint(av[0]), u1 = __float_as_uint(av[1]);
            const unsigned int u2 = __float_as_uint(av[2]), u3 = __float_as_uint(av[3]);
            uint2 wh2, wl2;
            wh2.x = __builtin_amdgcn_perm(u1, u0, 0x07060302);
            wh2.y = __builtin_amdgcn_perm(u3, u2, 0x07060302);
            const float l0 = av[0] - __uint_as_float(u0 & 0xFFFF0000u);
            const float l1 = av[1] - __uint_as_float(u1 & 0xFFFF0000u);
            const float l2 = av[2] - __uint_as_float(u2 & 0xFFFF0000u);
            const float l3 = av[3] - __uint_as_float(u3 & 0xFFFF0000u);
            wl2.x = __builtin_amdgcn_perm(__float_as_uint(l1), __float_as_uint(l0), 0x07060302);
            wl2.y = __builtin_amdgcn_perm(__float_as_uint(l3), __float_as_uint(l2), 0x07060302);

            const int boff = (otl * 32 + kg * 8) ^ ((prow & 7) << 4);
            *reinterpret_cast<uint2*>(ahb + boff) = wh2;
            *reinterpret_cast<uint2*>(alb + boff) = wl2;
        }

        // ---- B-frags for main GEMM (this half) ----
        bf16x8 bh[2], bl[2];
#pragma unroll
        for (int kkl = 0; kkl < 2; ++kkl) {
            const unsigned short* bb =
                w2f + ((size_t)(wv * 4 + 2 * h + kkl) * 2) * 512 + lane * 8;
            bh[kkl] = *reinterpret_cast<const bf16x8*>(bb);
            bl[kkl] = *reinterpret_cast<const bf16x8*>(bb + 512);
        }
        __syncthreads();                 // barrier B/D: tiles ready

        // ---- main MFMA ----
        const char* ahr = (const char*)Ah;
        const char* alr = (const char*)Al;
#pragma unroll
        for (int kkl = 0; kkl < 2; ++kkl) {
#pragma unroll
            for (int pt = 0; pt < 4; ++pt) {
                const int row = pt * 16 + n16;
                const int boff = ((kkl << 6) + (kg << 4)) ^ ((row & 7) << 4);
                bf16x8 afh = *reinterpret_cast<const bf16x8*>(ahr + row * 128 + boff);
                bf16x8 afl = *reinterpret_cast<const bf16x8*>(alr + row * 128 + boff);
                accM[pt] = __builtin_amdgcn_mfma_f32_16x16x32_bf16(afh, bh[kkl], accM[pt], 0, 0, 0);
                accM[pt] = __builtin_amdgcn_mfma_f32_16x16x32_bf16(afh, bl[kkl], accM[pt], 0, 0, 0);
                accM[pt] = __builtin_amdgcn_mfma_f32_16x16x32_bf16(afl, bh[kkl], accM[pt], 0, 0, 0);
            }
        }
    }

    // ---- epilogue ----
    {
        const int m = wv * 16 + n16;
        const float w3v = e_w3[m];
        const float b2v = e_b2[m];
#pragma unroll
        for (int pt = 0; pt < 4; ++pt) {
            float zs0 = fmaxf(accM[pt][0] + b2v, 0.f) * w3v;
            float zs1 = fmaxf(accM[pt][1] + b2v, 0.f) * w3v;
            float zs2 = fmaxf(accM[pt][2] + b2v, 0.f) * w3v;
            float zs3 = fmaxf(accM[pt][3] + b2v, 0.f) * w3v;
#pragma unroll
            for (int msk = 1; msk < 16; msk <<= 1) {
                zs0 += __shfl_xor(zs0, msk);
                zs1 += __shfl_xor(zs1, msk);
                zs2 += __shfl_xor(zs2, msk);
                zs3 += __shfl_xor(zs3, msk);
            }
            if (n16 == 0) {
                const int pr = pt * 16 + kg * 4;
                zsh[wv][pr]     = zs0;
                zsh[wv][pr + 1] = zs1;
                zsh[wv][pr + 2] = zs2;
                zsh[wv][pr + 3] = zs3;
            }
        }
    }
    __syncthreads();

    if (wv == 0) {
        float z = zsh[0][lane] + zsh[1][lane] + zsh[2][lane] + zsh[3][lane] + e_b3[0];
        out[pbase + lane] = fsigmoid_neg(-z);
    }
}

extern "C" void kernel_launch(void* const* d_in, const int* in_sizes, int n_in,
                              void* d_out, int out_size, void* d_ws, size_t ws_size,
                              hipStream_t stream) {
    const float* traj   = (const float*)d_in[0];
    const float* adj    = (const float*)d_in[1];
    const float* w_in   = (const float*)d_in[2];
    const float* b_in   = (const float*)d_in[3];
    const float* w_out  = (const float*)d_in[4];
    const float* b_out  = (const float*)d_in[5];
    const float* ln1g   = (const float*)d_in[6];
    const float* ln1b   = (const float*)d_in[7];
    const float* fw1    = (const float*)d_in[8];
    const float* fb1    = (const float*)d_in[9];
    const float* fw2    = (const float*)d_in[10];
    const float* fb2    = (const float*)d_in[11];
    const float* ln2g   = (const float*)d_in[12];
    const float* ln2b   = (const float*)d_in[13];
    const float* gcn_w  = (const float*)d_in[14];
    const float* gcn_b  = (const float*)d_in[15];
    const float* e_w1   = (const float*)d_in[16];
    const float* e_b1   = (const float*)d_in[17];
    const float* e_w2   = (const float*)d_in[18];
    const float* e_b2   = (const float*)d_in[19];
    const float* e_w3   = (const float*)d_in[20];
    const float* e_b3   = (const float*)d_in[21];

    float* ws    = (float*)d_ws;
    unsigned short* w2f = (unsigned short*)(ws + WS_W2F);
    float* txyT  = ws + WS_TXYT;
    float* partb = ws + WS_PART;     // gi colocated post-red3 (stride 256/row)
    float* gjT4  = ws + WS_GJT4;
    float* g1b   = ws + WS_GJT4;     // time-shared: dead before gjT4 written
    float* slotA = ws + WS_SLOTA;    // node0 -> g2b -> whf
    unsigned short* whf = (unsigned short*)(ws + WS_SLOTA);

    k_transformer<<<NN + 84, 128, 0, stream>>>(traj, w_in, b_in, w_out, b_out,
                                               ln1g, ln1b, fw1, fb1, fw2, fb2,
                                               ln2g, ln2b, e_w2,
                                               slotA, w2f, txyT);

    dim3 pgrid(NN / 8, JSPLIT);
    k_gcn_part<<<pgrid, 256, 0, stream>>>(adj, slotA, partb);
    k_gcn_red <<<NN / 4, 256, 0, stream>>>(partb, gcn_w, gcn_b, g1b);
    k_gcn_part<<<pgrid, 256, 0, stream>>>(adj, g1b, partb);
    k_gcn_red <<<NN / 4, 256, 0, stream>>>(partb, gcn_w + 4096, gcn_b + 64, slotA);
    k_gcn_part<<<pgrid, 256, 0, stream>>>(adj, slotA, partb);
    k_gcn_red3<<<NN / 4, 256, 0, stream>>>(partb, gcn_w + 8192, gcn_b + 128,
                                           e_w1, e_b1, gjT4, (unsigned int*)whf);

    k_edge<<<PP / 64, 256, 0, stream>>>(txyT, partb, gjT4, whf, w2f, e_b2,
                                        e_w3, e_b3, (float*)d_out);
}

// Round 13
// 313.363 us; speedup vs baseline: 1.0418x; 1.0418x over previous
//
#include <hip/hip_runtime.h>
#include <hip/hip_bf16.h>
#include <math.h>

#define NN 1536
#define TT 10
#define DD 64
#define NHEAD 4
#define HDIM 16
#define PP 1178880   // NN*(NN-1)/2 = 4605 * 256 exactly; = 18420 * 64
#define JSPLIT 4

// ws layout (float offsets) — lifetime-overlapped, total 727040 (proven safe):
//   W2F    0       (8192)
//   TXYT   8192    (30720)  -> 38912
//   PART   38912   (393216) -> 432128  [post-red3: row i floats 0..128 = gi, stride 256]
//   GJT4   432128  (196608) -> 628736  [g1b lives here during layers 1-2]
//   SLOTA  628736  (98304)  -> 727040  [node0 -> g2b]
#define WS_W2F   0
#define WS_TXYT  8192
#define WS_PART  38912
#define WS_GJT4  432128
#define WS_SLOTA 628736

using bf16x8 = __attribute__((ext_vector_type(8))) short;
using f32x4  = __attribute__((ext_vector_type(4))) float;

static __device__ __forceinline__ float fsqrt(float x) { return __builtin_amdgcn_sqrtf(x); }
static __device__ __forceinline__ float frcp(float x)  { return __builtin_amdgcn_rcpf(x); }
static __device__ __forceinline__ float fexp(float x)  {
    return __builtin_amdgcn_exp2f(x * 1.44269504088896f);
}
static __device__ __forceinline__ float fsigmoid_neg(float e_arg) {
    return frcp(1.f + fexp(e_arg));     // 1/(1+exp(e_arg))
}

static __device__ __forceinline__ unsigned short f2bf_rn(float f) {
    unsigned int u = __float_as_uint(f);
    unsigned int r = (u + 0x7FFFu + ((u >> 16) & 1u)) >> 16;
    return (unsigned short)r;
}
static __device__ __forceinline__ float bf2f(unsigned short h) {
    return __uint_as_float(((unsigned int)h) << 16);
}

static __device__ __forceinline__ float dot64(const float* __restrict__ a,
                                              const float* __restrict__ b) {
    float s = 0.f;
#pragma unroll
    for (int c = 0; c < 64; c += 4) {
        float4 av = *reinterpret_cast<const float4*>(a + c);
        float4 bv = *reinterpret_cast<const float4*>(b + c);
        s = fmaf(av.x, bv.x, s);
        s = fmaf(av.y, bv.y, s);
        s = fmaf(av.z, bv.z, s);
        s = fmaf(av.w, bv.w, s);
    }
    return s;
}

static __device__ __forceinline__ void invert_p(int p, int& io, int& jo) {
    const float Df = (float)((2 * NN - 1) * (2 * NN - 1) - 8 * p);
    int i = (int)(((float)(2 * NN - 1) - fsqrt(Df)) * 0.5f);
    i = i < 0 ? 0 : (i > NN - 2 ? NN - 2 : i);
    while (i * (2 * NN - 1 - i) / 2 > p) --i;
    while ((i + 1) * (2 * NN - 2 - i) / 2 <= p) ++i;
    io = i;
    jo = i + 1 + (p - i * (2 * NN - 1 - i) / 2);
}

// accumulate 16-wide chunk: acc += x[0..15] . w(4 float4 regs)
#define FMA16(acc, xr, w0, w1, w2, w3)                                   \
    {                                                                    \
        float4 x0 = *reinterpret_cast<const float4*>(xr);                \
        float4 x1 = *reinterpret_cast<const float4*>(xr + 4);            \
        float4 x2 = *reinterpret_cast<const float4*>(xr + 8);            \
        float4 x3 = *reinterpret_cast<const float4*>(xr + 12);           \
        acc = fmaf(x0.x, w0.x, acc); acc = fmaf(x0.y, w0.y, acc);        \
        acc = fmaf(x0.z, w0.z, acc); acc = fmaf(x0.w, w0.w, acc);        \
        acc = fmaf(x1.x, w1.x, acc); acc = fmaf(x1.y, w1.y, acc);        \
        acc = fmaf(x1.z, w1.z, acc); acc = fmaf(x1.w, w1.w, acc);        \
        acc = fmaf(x2.x, w2.x, acc); acc = fmaf(x2.y, w2.y, acc);        \
        acc = fmaf(x2.z, w2.z, acc); acc = fmaf(x2.w, w2.w, acc);        \
        acc = fmaf(x3.x, w3.x, acc); acc = fmaf(x3.y, w3.y, acc);        \
        acc = fmaf(x3.z, w3.z, acc); acc = fmaf(x3.w, w3.w, acc);        \
    }

// ---------------- Transformer encoder layer (+aux: w2f, txyT), 128 thr/block ----------------
__global__ __launch_bounds__(128) void k_transformer(
    const float* __restrict__ traj,
    const float* __restrict__ wqkv, const float* __restrict__ bqkv,
    const float* __restrict__ wo,   const float* __restrict__ bo,
    const float* __restrict__ g1,   const float* __restrict__ b1,
    const float* __restrict__ fw1,  const float* __restrict__ fb1,
    const float* __restrict__ fw2,  const float* __restrict__ fb2,
    const float* __restrict__ g2,   const float* __restrict__ b2,
    const float* __restrict__ e_w2,
    float* __restrict__ node_out, unsigned short* __restrict__ w2f,
    float* __restrict__ txyT)
{
    const int bid = blockIdx.x, tid = threadIdx.x;

    if (bid >= NN) {
        const int s = bid - NN;
        if (s < 64) {
#pragma unroll
            for (int q = 0; q < 2; ++q) {
                const int idx = s * 256 + q * 128 + tid;
                int e = idx & 7, lane = (idx >> 3) & 63;
                int half = (idx >> 9) & 1, kk = (idx >> 10) & 3, nt = (idx >> 12) & 3;
                int n = nt * 16 + (lane & 15);
                int k = kk * 32 + (lane >> 4) * 8 + e;
                float v = e_w2[n * 128 + k];
                unsigned short hi = f2bf_rn(v);
                unsigned short lo = f2bf_rn(v - bf2f(hi));
                w2f[idx] = half ? lo : hi;
            }
        } else {
            const int tc = s - 64;       // 0..19
            const int t = tc >> 1, c = tc & 1;
            for (int j = tid; j < NN; j += 128)
                txyT[(size_t)tc * NN + j] = traj[((size_t)j * TT + t) * DD + c];
        }
        return;
    }

    __shared__ __align__(16) float xs[TT][DD];
    __shared__ __align__(16) float qkvs[TT][3 * DD];
    __shared__ __align__(16) float cs[TT][DD];
    __shared__ __align__(16) float ys[TT][DD];
    __shared__ float mv[TT][2];

    const float* xg = traj + (size_t)bid * TT * DD;
    for (int idx = tid; idx < TT * DD; idx += 128)
        xs[idx / DD][idx % DD] = xg[idx];
    __syncthreads();

    // ---- QKV ----
    {
        float acc[TT];
        const float bq = bqkv[tid];
#pragma unroll
        for (int t = 0; t < TT; ++t) acc[t] = bq;
        const float* wrow = wqkv + (size_t)tid * DD;
#pragma unroll
        for (int c = 0; c < 4; ++c) {
            float4 w0 = *reinterpret_cast<const float4*>(wrow + 16 * c);
            float4 w1 = *reinterpret_cast<const float4*>(wrow + 16 * c + 4);
            float4 w2 = *reinterpret_cast<const float4*>(wrow + 16 * c + 8);
            float4 w3 = *reinterpret_cast<const float4*>(wrow + 16 * c + 12);
#pragma unroll
            for (int t = 0; t < TT; ++t)
                FMA16(acc[t], &xs[t][16 * c], w0, w1, w2, w3);
        }
#pragma unroll
        for (int t = 0; t < TT; ++t) qkvs[t][tid] = acc[t];

        const int o2 = 128 + (tid >> 1);
        const int t0 = (tid & 1) * 5;
        float acc2[5];
        const float bq2 = bqkv[o2];
#pragma unroll
        for (int tt = 0; tt < 5; ++tt) acc2[tt] = bq2;
        const float* wrow2 = wqkv + (size_t)o2 * DD;
#pragma unroll
        for (int c = 0; c < 4; ++c) {
            float4 w0 = *reinterpret_cast<const float4*>(wrow2 + 16 * c);
            float4 w1 = *reinterpret_cast<const float4*>(wrow2 + 16 * c + 4);
            float4 w2 = *reinterpret_cast<const float4*>(wrow2 + 16 * c + 8);
            float4 w3 = *reinterpret_cast<const float4*>(wrow2 + 16 * c + 12);
#pragma unroll
            for (int tt = 0; tt < 5; ++tt)
                FMA16(acc2[tt], &xs[t0 + tt][16 * c], w0, w1, w2, w3);
        }
#pragma unroll
        for (int tt = 0; tt < 5; ++tt) qkvs[t0 + tt][o2] = acc2[tt];
    }
    __syncthreads();

    // ---- attention ----
    if (tid < NHEAD * TT) {
        int h = tid / TT, t = tid % TT;
        float sc[TT];
        float mx = -1e30f;
#pragma unroll
        for (int s = 0; s < TT; ++s) {
            float a = 0.f;
#pragma unroll
            for (int d = 0; d < HDIM; ++d)
                a = fmaf(qkvs[t][h * HDIM + d], qkvs[s][DD + h * HDIM + d], a);
            a *= 0.25f;
            sc[s] = a;
            mx = fmaxf(mx, a);
        }
        float den = 0.f;
#pragma unroll
        for (int s = 0; s < TT; ++s) { sc[s] = fexp(sc[s] - mx); den += sc[s]; }
        float inv = frcp(den);
#pragma unroll
        for (int d = 0; d < HDIM; ++d) {
            float a = 0.f;
#pragma unroll
            for (int s = 0; s < TT; ++s)
                a = fmaf(sc[s], qkvs[s][2 * DD + h * HDIM + d], a);
            cs[t][h * HDIM + d] = a * inv;
        }
    }
    __syncthreads();

    // ---- out-proj + residual ----
    {
        const int o = tid & 63, t0 = (tid >> 6) * 5;
        float acc[5];
        const float bv = bo[o];
#pragma unroll
        for (int tt = 0; tt < 5; ++tt) acc[tt] = bv;
        const float* wrow = wo + (size_t)o * DD;
#pragma unroll
        for (int c = 0; c < 4; ++c) {
            float4 w0 = *reinterpret_cast<const float4*>(wrow + 16 * c);
            float4 w1 = *reinterpret_cast<const float4*>(wrow + 16 * c + 4);
            float4 w2 = *reinterpret_cast<const float4*>(wrow + 16 * c + 8);
            float4 w3 = *reinterpret_cast<const float4*>(wrow + 16 * c + 12);
#pragma unroll
            for (int tt = 0; tt < 5; ++tt)
                FMA16(acc[tt], &cs[t0 + tt][16 * c], w0, w1, w2, w3);
        }
#pragma unroll
        for (int tt = 0; tt < 5; ++tt)
            ys[t0 + tt][o] = xs[t0 + tt][o] + acc[tt];
    }
    __syncthreads();

    // ---- LN1 stats ----
    {
        const int t8 = tid >> 3, s8 = tid & 7;
        if (t8 < TT) {
            const float* yr = &ys[t8][s8 * 8];
            float s1 = 0.f;
#pragma unroll
            for (int c = 0; c < 8; c += 4) {
                float4 v = *reinterpret_cast<const float4*>(yr + c);
                s1 += (v.x + v.y) + (v.z + v.w);
            }
#pragma unroll
            for (int m = 1; m < 8; m <<= 1) s1 += __shfl_xor(s1, m);
            const float mean = s1 * (1.f / DD);
            float s2 = 0.f;
#pragma unroll
            for (int c = 0; c < 8; c += 4) {
                float4 v = *reinterpret_cast<const float4*>(yr + c);
                float d0 = v.x - mean, d1 = v.y - mean, d2 = v.z - mean, d3 = v.w - mean;
                s2 = fmaf(d0, d0, fmaf(d1, d1, fmaf(d2, d2, fmaf(d3, d3, s2))));
            }
#pragma unroll
            for (int m = 1; m < 8; m <<= 1) s2 += __shfl_xor(s2, m);
            if (s8 == 0) {
                mv[t8][0] = mean;
                mv[t8][1] = rsqrtf(s2 * (1.f / DD) + 1e-5f);
            }
        }
    }
    __syncthreads();
    for (int idx = tid; idx < TT * DD; idx += 128) {
        int t = idx / DD, o = idx % DD;
        xs[t][o] = (ys[t][o] - mv[t][0]) * mv[t][1] * g1[o] + b1[o];
    }
    __syncthreads();

    // ---- FF1 ----
    {
        const int pcol = tid & 63, t0 = (tid >> 6) * 5;
        float acc[5];
        const float bv = fb1[pcol];
#pragma unroll
        for (int tt = 0; tt < 5; ++tt) acc[tt] = bv;
        const float* wrow = fw1 + (size_t)pcol * DD;
#pragma unroll
        for (int c = 0; c < 4; ++c) {
            float4 w0 = *reinterpret_cast<const float4*>(wrow + 16 * c);
            float4 w1 = *reinterpret_cast<const float4*>(wrow + 16 * c + 4);
            float4 w2 = *reinterpret_cast<const float4*>(wrow + 16 * c + 8);
            float4 w3 = *reinterpret_cast<const float4*>(wrow + 16 * c + 12);
#pragma unroll
            for (int tt = 0; tt < 5; ++tt)
                FMA16(acc[tt], &xs[t0 + tt][16 * c], w0, w1, w2, w3);
        }
#pragma unroll
        for (int tt = 0; tt < 5; ++tt)
            cs[t0 + tt][pcol] = fmaxf(acc[tt], 0.f);
    }
    __syncthreads();

    // ---- FF2 + residual ----
    {
        const int o = tid & 63, t0 = (tid >> 6) * 5;
        float acc[5];
        const float bv = fb2[o];
#pragma unroll
        for (int tt = 0; tt < 5; ++tt) acc[tt] = bv;
        const float* wrow = fw2 + (size_t)o * DD;
#pragma unroll
        for (int c = 0; c < 4; ++c) {
            float4 w0 = *reinterpret_cast<const float4*>(wrow + 16 * c);
            float4 w1 = *reinterpret_cast<const float4*>(wrow + 16 * c + 4);
            float4 w2 = *reinterpret_cast<const float4*>(wrow + 16 * c + 8);
            float4 w3 = *reinterpret_cast<const float4*>(wrow + 16 * c + 12);
#pragma unroll
            for (int tt = 0; tt < 5; ++tt)
                FMA16(acc[tt], &cs[t0 + tt][16 * c], w0, w1, w2, w3);
        }
#pragma unroll
        for (int tt = 0; tt < 5; ++tt)
            ys[t0 + tt][o] = xs[t0 + tt][o] + acc[tt];
    }
    __syncthreads();

    // ---- LN2 stats ----
    {
        const int t8 = tid >> 3, s8 = tid & 7;
        if (t8 < TT) {
            const float* yr = &ys[t8][s8 * 8];
            float s1 = 0.f;
#pragma unroll
            for (int c = 0; c < 8; c += 4) {
                float4 v = *reinterpret_cast<const float4*>(yr + c);
                s1 += (v.x + v.y) + (v.z + v.w);
            }
#pragma unroll
            for (int m = 1; m < 8; m <<= 1) s1 += __shfl_xor(s1, m);
            const float mean = s1 * (1.f / DD);
            float s2 = 0.f;
#pragma unroll
            for (int c = 0; c < 8; c += 4) {
                float4 v = *reinterpret_cast<const float4*>(yr + c);
                float d0 = v.x - mean, d1 = v.y - mean, d2 = v.z - mean, d3 = v.w - mean;
                s2 = fmaf(d0, d0, fmaf(d1, d1, fmaf(d2, d2, fmaf(d3, d3, s2))));
            }
#pragma unroll
            for (int m = 1; m < 8; m <<= 1) s2 += __shfl_xor(s2, m);
            if (s8 == 0) {
                mv[t8][0] = mean;
                mv[t8][1] = rsqrtf(s2 * (1.f / DD) + 1e-5f);
            }
        }
    }
    __syncthreads();

    if (tid < DD) {
        float acc = 0.f;
#pragma unroll
        for (int t = 0; t < TT; ++t)
            acc += (ys[t][tid] - mv[t][0]) * mv[t][1];
        node_out[bid * DD + tid] = acc * g2[tid] * (1.f / TT) + b2[tid];
    }
}

// ---------------- GCN: partial A@X over j-chunk; part layout [i][jc][64] ----------------
__global__ __launch_bounds__(256) void k_gcn_part(
    const float* __restrict__ A, const float* __restrict__ X,
    float* __restrict__ part)
{
    const int tid = threadIdx.x;
    const int r = tid >> 5;
    const int cp = tid & 31;
    const int i = blockIdx.x * 8 + r;
    const int jc = blockIdx.y;
    const int j0 = jc * (NN / JSPLIT);

    const float* arow = A + (size_t)i * NN + j0;
    const float* xp = X + (size_t)j0 * 64 + 2 * cp;

    float a0 = 0.f, a1 = 0.f;
#pragma unroll 4
    for (int j = 0; j < NN / JSPLIT; ++j) {
        float av = arow[j];
        float2 xv = *reinterpret_cast<const float2*>(xp + (size_t)j * 64);
        a0 = fmaf(av, xv.x, a0);
        a1 = fmaf(av, xv.y, a1);
    }
    float2* op = reinterpret_cast<float2*>(part + ((size_t)i * JSPLIT + jc) * 64 + 2 * cp);
    *op = make_float2(a0, a1);
}

// ---------------- GCN red (layers 1,2) ----------------
__global__ __launch_bounds__(256) void k_gcn_red(
    const float* __restrict__ part, const float* __restrict__ W,
    const float* __restrict__ b, float* __restrict__ Y)
{
    __shared__ __align__(16) float yrow[4][68];
    const int o = threadIdx.x & 63, r = threadIdx.x >> 6;
    const int i = blockIdx.x * 4 + r;

    float s = 0.f;
#pragma unroll
    for (int jc = 0; jc < JSPLIT; ++jc)
        s += part[((size_t)i * JSPLIT + jc) * 64 + o];
    yrow[r][o] = s;
    __syncthreads();

    float z = b[o] + dot64(&yrow[r][0], W + o * 64);
    Y[(size_t)i * 64 + o] = fmaxf(z, 0.f);
}

// ---------------- GCN red layer 3 + fused edge-prep (gi into part rows, gjT4) ----------------
__global__ __launch_bounds__(256) void k_gcn_red3(
    float* __restrict__ part, const float* __restrict__ W,
    const float* __restrict__ b,
    const float* __restrict__ e_w1, const float* __restrict__ e_b1,
    float* __restrict__ gjT4)
{
    __shared__ __align__(16) float yrow[4][68];
    __shared__ __align__(16) float nrow[4][68];
    const int tid = threadIdx.x;
    const int o = tid & 63, r = tid >> 6;
    const int i0 = blockIdx.x * 4;

    float s = 0.f;
#pragma unroll
    for (int jc = 0; jc < JSPLIT; ++jc)
        s += part[((size_t)(i0 + r) * JSPLIT + jc) * 64 + o];
    yrow[r][o] = s;
    __syncthreads();

    float z = b[o] + dot64(&yrow[r][0], W + o * 64);
    nrow[r][o] = fmaxf(z, 0.f);
    __syncthreads();

    // gi into part's own rows (stride 256), gjT4 quad layout
#pragma unroll
    for (int pass = 0; pass < 2; ++pass) {
        const int idx = pass * 256 + tid;
        const int rr = idx >> 7, oo = idx & 127;
        part[(size_t)(i0 + rr) * 256 + oo] =
            e_b1[oo] + dot64(&nrow[rr][0], e_w1 + oo * 138);
    }
#pragma unroll
    for (int pass = 0; pass < 2; ++pass) {
        const int idx = pass * 256 + tid;
        const int rr = idx >> 7, oo = idx & 127;
        float v = dot64(&nrow[rr][0], e_w1 + oo * 138 + 64);
        gjT4[((size_t)(oo >> 2) * NN + (i0 + rr)) * 4 + (oo & 3)] = v;
    }
}

// ---------------- edge predictor: MFMA, 64 pairs/block, 4 waves, half-K tiles ----------------
// LDS exactly 20224 B -> 8 blocks/CU; hist/dmin stores deferred to kernel end
__global__ __launch_bounds__(256, 8) void k_edge(
    const float* __restrict__ txyT,
    const float* __restrict__ gi_t,      // stride 256 per i (part rows)
    const float* __restrict__ gjT4,
    const float* __restrict__ e_w1,
    const unsigned short* __restrict__ w2f,
    const float* __restrict__ e_b2,
    const float* __restrict__ e_w3, const float* __restrict__ e_b3,
    float* __restrict__ out)
{
    __shared__ __align__(16) unsigned short Ah[64 * 64];   // 8192 B
    __shared__ __align__(16) unsigned short Al[64 * 64];   // 8192 B
    __shared__ __align__(16) float hs[64][11];             // 2816 B
    __shared__ __align__(16) float zsh[4][64];             // 1024 B

    const int tid  = threadIdx.x;
    const int lane = tid & 63;
    const int wv   = __builtin_amdgcn_readfirstlane(tid >> 6);  // wave 0..3
    const int p    = blockIdx.x * 64 + lane;

    int pi, pj;
    invert_p(p, pi, pj);

    // ---- hist + dmin: wave 0 -> LDS only (stores deferred) ----
    float dmin = 3.4e38f;
    if (wv == 0) {
#pragma unroll
        for (int t = 0; t < 10; ++t) {
            float dx = txyT[(size_t)(2 * t) * NN + pi] - txyT[(size_t)(2 * t) * NN + pj];
            float dy = txyT[(size_t)(2 * t + 1) * NN + pi] - txyT[(size_t)(2 * t + 1) * NN + pj];
            float d = fsqrt(fmaf(dx, dx, dy * dy));
            dmin = fminf(dmin, d);
            hs[lane][t] = fsigmoid_neg(50.f - 10.f * d);   // sigmoid(10d-50)
        }
    }
    __syncthreads();

    float hist[10];
#pragma unroll
    for (int t = 0; t < 10; ++t) hist[t] = hs[lane][t];

    f32x4 acc[4];
#pragma unroll
    for (int pt = 0; pt < 4; ++pt) acc[pt] = (f32x4){0.f, 0.f, 0.f, 0.f};

#pragma unroll
    for (int h = 0; h < 2; ++h) {
        // ---- phase 1: 16 o's for o-window [h*64 + wv*16, +16) ----
        const int ob = h * 64 + wv * 16;
        const float* giRow = gi_t + (size_t)pi * 256 + ob;
        unsigned int ahp[8], alp[8];
#pragma unroll
        for (int q2 = 0; q2 < 4; ++q2) {
            const int o = ob + 4 * q2;
            const float4 gi4 = *reinterpret_cast<const float4*>(giRow + 4 * q2);
            const float4 gj4 = *reinterpret_cast<const float4*>(
                gjT4 + ((size_t)(o >> 2) * NN + pj) * 4);
            float av[4];
#pragma unroll
            for (int k = 0; k < 4; ++k) {
                float a = (&gi4.x)[k] + (&gj4.x)[k];
                const float* wh = e_w1 + (o + k) * 138 + 128;   // uniform -> scalar
#pragma unroll
                for (int t = 0; t < 10; ++t) a = fmaf(hist[t], wh[t], a);
                av[k] = fmaxf(a, 0.f);
            }
            const unsigned int u0 = __float_as_uint(av[0]), u1 = __float_as_uint(av[1]);
            const unsigned int u2 = __float_as_uint(av[2]), u3 = __float_as_uint(av[3]);
            ahp[2 * q2]     = __builtin_amdgcn_perm(u1, u0, 0x07060302);
            ahp[2 * q2 + 1] = __builtin_amdgcn_perm(u3, u2, 0x07060302);
            const float l0 = av[0] - __uint_as_float(u0 & 0xFFFF0000u);
            const float l1 = av[1] - __uint_as_float(u1 & 0xFFFF0000u);
            const float l2 = av[2] - __uint_as_float(u2 & 0xFFFF0000u);
            const float l3 = av[3] - __uint_as_float(u3 & 0xFFFF0000u);
            alp[2 * q2]     = __builtin_amdgcn_perm(__float_as_uint(l1), __float_as_uint(l0), 0x07060302);
            alp[2 * q2 + 1] = __builtin_amdgcn_perm(__float_as_uint(l3), __float_as_uint(l2), 0x07060302);
        }

        if (h == 1) __syncthreads();    // all waves done reading half-0 tiles

        // write tiles: row = lane (128 B rows), XOR row swizzle
        char* ahb = (char*)Ah + lane * 128;
        char* alb = (char*)Al + lane * 128;
#pragma unroll
        for (int c = 0; c < 2; ++c) {
            const int boff = ((wv << 5) + (c << 4)) ^ ((lane & 7) << 4);
            *reinterpret_cast<uint4*>(ahb + boff) = *reinterpret_cast<uint4*>(&ahp[4 * c]);
            *reinterpret_cast<uint4*>(alb + boff) = *reinterpret_cast<uint4*>(&alp[4 * c]);
        }

        // B-frags for this half: global kk = 2h + kkl
        bf16x8 bh[2], bl[2];
#pragma unroll
        for (int kkl = 0; kkl < 2; ++kkl) {
            const unsigned short* bb =
                w2f + ((size_t)(wv * 4 + 2 * h + kkl) * 2) * 512 + lane * 8;
            bh[kkl] = *reinterpret_cast<const bf16x8*>(bb);
            bl[kkl] = *reinterpret_cast<const bf16x8*>(bb + 512);
        }
        __syncthreads();

        // ---- MFMA: 2 kkl x 4 pt x 3 terms ----
        const char* ahr = (const char*)Ah;
        const char* alr = (const char*)Al;
#pragma unroll
        for (int kkl = 0; kkl < 2; ++kkl) {
#pragma unroll
            for (int pt = 0; pt < 4; ++pt) {
                const int row = pt * 16 + (lane & 15);
                const int boff = ((kkl << 6) + ((lane >> 4) << 4)) ^ ((row & 7) << 4);
                bf16x8 afh = *reinterpret_cast<const bf16x8*>(ahr + row * 128 + boff);
                bf16x8 afl = *reinterpret_cast<const bf16x8*>(alr + row * 128 + boff);
                acc[pt] = __builtin_amdgcn_mfma_f32_16x16x32_bf16(afh, bh[kkl], acc[pt], 0, 0, 0);
                acc[pt] = __builtin_amdgcn_mfma_f32_16x16x32_bf16(afh, bl[kkl], acc[pt], 0, 0, 0);
                acc[pt] = __builtin_amdgcn_mfma_f32_16x16x32_bf16(afl, bh[kkl], acc[pt], 0, 0, 0);
            }
        }
    }

    // ---- epilogue ----
    {
        const int m = wv * 16 + (lane & 15);
        const float w3v = e_w3[m];
        const float b2v = e_b2[m];
#pragma unroll
        for (int pt = 0; pt < 4; ++pt) {
            float zs0 = fmaxf(acc[pt][0] + b2v, 0.f) * w3v;
            float zs1 = fmaxf(acc[pt][1] + b2v, 0.f) * w3v;
            float zs2 = fmaxf(acc[pt][2] + b2v, 0.f) * w3v;
            float zs3 = fmaxf(acc[pt][3] + b2v, 0.f) * w3v;
#pragma unroll
            for (int msk = 1; msk < 16; msk <<= 1) {
                zs0 += __shfl_xor(zs0, msk);
                zs1 += __shfl_xor(zs1, msk);
                zs2 += __shfl_xor(zs2, msk);
                zs3 += __shfl_xor(zs3, msk);
            }
            if ((lane & 15) == 0) {
                const int pr = pt * 16 + (lane >> 4) * 4;
                zsh[wv][pr]     = zs0;
                zsh[wv][pr + 1] = zs1;
                zsh[wv][pr + 2] = zs2;
                zsh[wv][pr + 3] = zs3;
            }
        }
    }
    __syncthreads();

    // ---- deferred stores: prob + dmin + hist (hs still live) ----
    if (wv == 0) {
        float z = zsh[0][lane] + zsh[1][lane] + zsh[2][lane] + zsh[3][lane] + e_b3[0];
        out[p] = fsigmoid_neg(-z);
        out[PP + (size_t)p] = dmin;
        float* hp = out + 2 * (size_t)PP + (size_t)p * 10;
#pragma unroll
        for (int t = 0; t < 10; ++t) hp[t] = hs[lane][t];
    }
}

extern "C" void kernel_launch(void* const* d_in, const int* in_sizes, int n_in,
                              void* d_out, int out_size, void* d_ws, size_t ws_size,
                              hipStream_t stream) {
    const float* traj   = (const float*)d_in[0];
    const float* adj    = (const float*)d_in[1];
    const float* w_in   = (const float*)d_in[2];
    const float* b_in   = (const float*)d_in[3];
    const float* w_out  = (const float*)d_in[4];
    const float* b_out  = (const float*)d_in[5];
    const float* ln1g   = (const float*)d_in[6];
    const float* ln1b   = (const float*)d_in[7];
    const float* fw1    = (const float*)d_in[8];
    const float* fb1    = (const float*)d_in[9];
    const float* fw2    = (const float*)d_in[10];
    const float* fb2    = (const float*)d_in[11];
    const float* ln2g   = (const float*)d_in[12];
    const float* ln2b   = (const float*)d_in[13];
    const float* gcn_w  = (const float*)d_in[14];
    const float* gcn_b  = (const float*)d_in[15];
    const float* e_w1   = (const float*)d_in[16];
    const float* e_b1   = (const float*)d_in[17];
    const float* e_w2   = (const float*)d_in[18];
    const float* e_b2   = (const float*)d_in[19];
    const float* e_w3   = (const float*)d_in[20];
    const float* e_b3   = (const float*)d_in[21];

    float* ws    = (float*)d_ws;
    unsigned short* w2f = (unsigned short*)(ws + WS_W2F);
    float* txyT  = ws + WS_TXYT;
    float* partb = ws + WS_PART;     // gi colocated post-red3 (stride 256/row)
    float* gjT4  = ws + WS_GJT4;
    float* g1b   = ws + WS_GJT4;     // time-shared: dead before gjT4 written
    float* slotA = ws + WS_SLOTA;    // node0 -> g2b

    k_transformer<<<NN + 84, 128, 0, stream>>>(traj, w_in, b_in, w_out, b_out,
                                               ln1g, ln1b, fw1, fb1, fw2, fb2,
                                               ln2g, ln2b, e_w2,
                                               slotA, w2f, txyT);

    dim3 pgrid(NN / 8, JSPLIT);
    k_gcn_part<<<pgrid, 256, 0, stream>>>(adj, slotA, partb);
    k_gcn_red <<<NN / 4, 256, 0, stream>>>(partb, gcn_w, gcn_b, g1b);
    k_gcn_part<<<pgrid, 256, 0, stream>>>(adj, g1b, partb);
    k_gcn_red <<<NN / 4, 256, 0, stream>>>(partb, gcn_w + 4096, gcn_b + 64, slotA);
    k_gcn_part<<<pgrid, 256, 0, stream>>>(adj, slotA, partb);
    k_gcn_red3<<<NN / 4, 256, 0, stream>>>(partb, gcn_w + 8192, gcn_b + 128,
                                           e_w1, e_b1, gjT4);

    k_edge<<<PP / 64, 256, 0, stream>>>(txyT, partb, gjT4, e_w1, w2f, e_b2,
                                        e_w3, e_b3, (float*)d_out);
}